// Round 27
// baseline (159.618 us; speedup 1.0000x reference)
//
#include <hip/hip_runtime.h>
#include <math.h>

#define Bn 32
#define Pn 42840
#define On 64
#define NIn 8
#define Cn 11
#define ATT_N (32*56*96)
#define THRESHOLD_F 0.4f
#define THETA_F 0.1f
#define CHn 16
#define CHUNK ((Pn + CHn - 1)/CHn)
#define DBLK 42         /* phaseD blocks per batch */
#define WPB  (DBLK*4)   /* phaseD waves per batch = 168 */
#define FP 4            /* priors per thread in matchAB */
#define FBLK ((Pn + 256*FP - 1)/(256*FP))   /* 42 blocks per batch */

// opaque register pin: read-write empty asm -> compiler cannot rematerialize
#define PINF(x) asm volatile("" : "+v"(x))

// ---- fused match: ONE pass over the O x P iou matrix reduces BOTH axes ----
// __launch_bounds__(256,8): 8 waves/SIMD -> up to 8 blocks/CU co-resident
// (the old (256,4) self-capped occupancy at 50%; VGPR=40 fits the 64 cap)
__global__ void __launch_bounds__(256, 8)
matchAB_kernel(const float* __restrict__ boxes,
               const float* __restrict__ ign,
               const float* __restrict__ priors,
               float* __restrict__ ov_prior,
               int* __restrict__ objinfo,
               unsigned long long* __restrict__ key_obj){
  __shared__ float4 sbox[On];
  __shared__ float  sar[On];
  __shared__ float4 ibox[NIn];
  __shared__ float  iar[NIn];
  __shared__ unsigned long long skey[On];
  int b = blockIdx.y, t = threadIdx.x;
  if (t < On){
    float4 v = ((const float4*)boxes)[b*On + t];
    sbox[t]=v; sar[t]=(v.z-v.x)*(v.w-v.y);
    skey[t]=0ull;
  } else if (t < On+NIn){
    int o = t - On;
    float4 v = ((const float4*)ign)[b*NIn + o];
    ibox[o]=v; iar[o]=(v.z-v.x)*(v.w-v.y);
  }
  __syncthreads();
  int p0 = (blockIdx.x*256 + t)*FP;
  bool active = (p0 < Pn);          // Pn%4==0 -> all 4 valid when active
  float px1[FP], py1[FP], px2[FP], py2[FP], pab[FP];
  #pragma unroll
  for (int q=0;q<FP;q++){
    float4 pc = active ? ((const float4*)priors)[p0+q]
                       : make_float4(0.f,0.f,0.f,0.f);
    px1[q]=pc.x - pc.z*0.5f; py1[q]=pc.y - pc.w*0.5f;
    px2[q]=pc.x + pc.z*0.5f; py2[q]=pc.y + pc.w*0.5f;
    pab[q]=(px2[q]-px1[q])*(py2[q]-py1[q]);
    PINF(px1[q]); PINF(py1[q]); PINF(px2[q]); PINF(py2[q]); PINF(pab[q]);
  }
  float best[FP]; int bo[FP];
  #pragma unroll
  for (int q=0;q<FP;q++){ best[q]=-1.0f; bo[q]=0; }
  #pragma unroll 1
  for (int o=0;o<On;o++){
    float4 ob = sbox[o];
    float oar = sar[o];
    float cmax=-1.0f; unsigned cp=0u;
    #pragma unroll
    for (int q=0;q<FP;q++){
      float ltx=fmaxf(ob.x,px1[q]), lty=fmaxf(ob.y,py1[q]);
      float rbx=fminf(ob.z,px2[q]), rby=fminf(ob.w,py2[q]);
      float w=fmaxf(rbx-ltx,0.0f), h=fmaxf(rby-lty,0.0f);
      float inter=w*h;
      float uni=(oar+pab[q])-inter;
      float iou = inter * __builtin_amdgcn_rcpf(uni);
      if (iou > best[q]){ best[q]=iou; bo[q]=o; }   // row argmax, first-occurrence
      if (iou > cmax){ cmax=iou; cp=(unsigned)(p0+q); } // col local, smallest p
    }
    // float-only wave max, then lowest-lane-among-ties = smallest p
    float wm = cmax;
    #pragma unroll
    for (int d=32; d>0; d>>=1)
      wm = fmaxf(wm, __shfl_xor(wm, d, 64));
    unsigned long long ball = __ballot(cmax == wm);
    int leader = __ffsll((long long)ball) - 1;
    if (active && (t & 63) == leader){
      unsigned long long key = ((unsigned long long)__float_as_uint(wm)<<32)
                             | (unsigned long long)(0xFFFFFFFFu - cp);
      atomicMax(&skey[o], key);
    }
  }
  // ignored regions: per-prior max only
  float ib[FP];
  #pragma unroll
  for (int q=0;q<FP;q++) ib[q]=-1.0f;
  #pragma unroll
  for (int j=0;j<NIn;j++){
    float4 jb = ibox[j];
    float jar = iar[j];
    #pragma unroll
    for (int q=0;q<FP;q++){
      float ltx=fmaxf(jb.x,px1[q]), lty=fmaxf(jb.y,py1[q]);
      float rbx=fminf(jb.z,px2[q]), rby=fminf(jb.w,py2[q]);
      float w=fmaxf(rbx-ltx,0.0f), h=fmaxf(rby-lty,0.0f);
      float inter=w*h;
      float uni=(jar+pab[q])-inter;
      ib[q] = fmaxf(ib[q], inter * __builtin_amdgcn_rcpf(uni));
    }
  }
  if (active){
    size_t bp0 = (size_t)b*Pn + p0;
    int in_[FP];
    #pragma unroll
    for (int q=0;q<FP;q++)
      in_[q] = bo[q] | ((ib[q] >= THETA_F) ? 256 : 0);
    *(float4*)(ov_prior + bp0) = make_float4(best[0],best[1],best[2],best[3]);
    *(int4*)(objinfo + bp0)    = make_int4(in_[0],in_[1],in_[2],in_[3]);
  }
  __syncthreads();
  if (t < On) atomicMax(&key_obj[(size_t)b*On + t], skey[t]);
}

// ---- phase D: 4 priors/thread + folded seg + fused phaseC winner-list ----
__global__ void __launch_bounds__(256, 4)
phaseD_kernel(const float* __restrict__ odm_locs,
              const float* __restrict__ odm_scores,
              const float* __restrict__ boxes,
              const int* __restrict__ labels,
              const float* __restrict__ priors,
              const float* __restrict__ ov_prior,
              const int* __restrict__ objinfo,
              const float* __restrict__ att,
              const unsigned long long* __restrict__ key_obj,
              float* __restrict__ conf_neg,
              float* __restrict__ ploc,
              float* __restrict__ pconf,
              int* __restrict__ ppos,
              float* __restrict__ pseg){
  int b = blockIdx.y;
  int t = threadIdx.x;
  // winner list for this block's prior range [pbase, pbase+1024)
  __shared__ int wl_p[On];
  __shared__ int wl_rank[On];
  __shared__ int wl_n;
  int pbase = blockIdx.x*1024;
  if (t == 0) wl_n = 0;
  __syncthreads();
  if (t < On){                          // first wave only
    unsigned long long k = key_obj[(size_t)b*On + t];
    bool valid = (unsigned)(k>>32) > 0u;
    unsigned long long ball = __ballot(valid);
    int rank = (int)__popcll(ball & ((1ull<<t) - 1ull));  // cumsum(valid)-1
    if (valid){
      int p = (int)(0xFFFFFFFFu - (unsigned)(k & 0xFFFFFFFFu));
      if (p >= pbase && p < pbase + 1024){
        int idx = atomicAdd(&wl_n, 1);
        wl_p[idx] = p; wl_rank[idx] = rank;
      }
    }
  }
  // folded seg: phaseD has 1344*256 = 344064 threads >= ATT_N = 172032
  int gid = (b*DBLK + blockIdx.x)*256 + t;
  float segv = 0.0f;
  if (gid < ATT_N) segv = fmaxf(log1pf(-att[gid]), -100.0f);
  __syncthreads();
  int nwl = wl_n;
  int p0 = pbase + t*4;
  float locv = 0.0f, confpv = 0.0f; int posv = 0;
  if (p0 < Pn){                           // Pn%4==0 -> all 4 priors valid
    size_t bp0 = (size_t)b*Pn + p0;
    float4 sc4[11];
    const float4* src = (const float4*)(odm_scores + bp0*Cn);  // 16B-aligned
    #pragma unroll
    for (int i=0;i<11;i++) sc4[i] = src[i];
    int4   info4 = *(const int4*)(objinfo + bp0);
    float4 ovp4  = *(const float4*)(ov_prior + bp0);
    const float* sc = (const float*)sc4;   // constant indices only (post-unroll)
    float cn[4];
    #pragma unroll
    for (int j=0;j<4;j++){
      int info = (&info4.x)[j];
      int obj = info & 0xFF;
      bool ignored = (info & 256) != 0;
      float ov = (&ovp4.x)[j];
      // winner override: obj -> rank (max over duplicates == last-write-wins), ov -> 1.0
      int ovr = -1;
      for (int i=0;i<nwl;i++)
        if (wl_p[i] == p0+j) ovr = max(ovr, wl_rank[i]);
      if (ovr >= 0){ obj = ovr; ov = 1.0f; }
      int label = labels[b*On + obj];
      if (ov < THRESHOLD_F) label = 0;
      bool pos = label > 0;
      float m = sc[j*Cn];
      #pragma unroll
      for (int c=1;c<Cn;c++) m = fmaxf(m, sc[j*Cn+c]);
      float se = 0.0f, slab = 0.0f;
      #pragma unroll
      for (int c=0;c<Cn;c++){
        float v = sc[j*Cn+c];
        se += expf(v-m);
        if (c == label) slab = v;          // c is compile-time -> cndmask chain
      }
      float conf = logf(se) - (slab-m);
      cn[j] = (pos || ignored) ? 0.0f : conf;
      if (pos){
        posv += 1; confpv += conf;
        size_t bp = bp0 + j;
        float4 pc = ((const float4*)priors)[p0+j];
        float4 g  = ((const float4*)odm_locs)[bp];
        float cx = g.x*pc.z/10.0f + pc.x;
        float cy = g.y*pc.w/10.0f + pc.y;
        float w  = expf(g.z/5.0f)*pc.z;
        float h  = expf(g.w/5.0f)*pc.w;
        float dx1 = cx - w/2.0f, dy1 = cy - h/2.0f;
        float dx2 = cx + w/2.0f, dy2 = cy + h/2.0f;
        const float* gt = boxes + ((size_t)b*On + obj)*4;
        float gx1=gt[0], gy1=gt[1], gx2=gt[2], gy2=gt[3];
        float ltx=fmaxf(dx1,gx1), lty=fmaxf(dy1,gy1);
        float rbx=fminf(dx2,gx2), rby=fminf(dy2,gy2);
        float iw=fmaxf(rbx-ltx,0.0f), ih=fmaxf(rby-lty,0.0f);
        float inter=iw*ih;
        float ap=(dx2-dx1)*(dy2-dy1);
        float ag=(gx2-gx1)*(gy2-gy1);
        float iou = inter/((ap+ag)-inter);
        float cpx=(dx1+dx2)/2.0f, cpy=(dy1+dy2)/2.0f;
        float cgx=(gx1+gx2)/2.0f, cgy=(gy1+gy2)/2.0f;
        float ddx=cpx-cgx, ddy=cpy-cgy;
        float inter_diag = ddx*ddx + ddy*ddy;
        float cltx=fminf(dx1,gx1), clty=fminf(dy1,gy1);
        float crbx=fmaxf(dx2,gx2), crby=fmaxf(dy2,gy2);
        float odx=crbx-cltx, ody=crby-clty;
        float outer_diag = odx*odx + ody*ody;
        float diou = fminf(fmaxf(iou - inter_diag/outer_diag, -1.0f), 1.0f);
        locv += 1.0f - diou;
      }
    }
    *(float4*)(conf_neg + bp0) = make_float4(cn[0],cn[1],cn[2],cn[3]);
  }
  // per-wave butterfly reduction, lane 0 writes a unique slot -> zero contention
  #pragma unroll
  for (int d=32; d>0; d>>=1){
    locv   += __shfl_xor(locv,   d, 64);
    confpv += __shfl_xor(confpv, d, 64);
    posv   += __shfl_xor(posv,   d, 64);
    segv   += __shfl_xor(segv,   d, 64);
  }
  if ((t & 63) == 0){
    int widx = b*WPB + (blockIdx.x<<2) + (t>>6);
    ploc[widx]  = locv;
    pconf[widx] = confpv;
    ppos[widx]  = posv;
    pseg[widx]  = segv;
  }
}

// ---- phase E: SINGLE-round 12-bit radix select with per-bin (count,sum) ----
__global__ void histE_kernel(const float* __restrict__ conf_neg,
                             unsigned* __restrict__ gcnt,
                             float* __restrict__ gsum){
  int b = blockIdx.y, c = blockIdx.x, t = threadIdx.x;
  __shared__ unsigned hc[4096];
  __shared__ float    hs[4096];
  for (int i=t;i<4096;i+=256){ hc[i]=0u; hs[i]=0.0f; }
  __syncthreads();
  const float* cn = conf_neg + (size_t)b*Pn;
  int p0 = c*CHUNK, p1 = min(Pn, p0+CHUNK);
  for (int p=p0+t; p<p1; p+=256){
    float v = cn[p];
    unsigned d = __float_as_uint(v)>>20;   // v >= 0 -> uint order == float order
    atomicAdd(&hc[d],1u); atomicAdd(&hs[d],v);
  }
  __syncthreads();
  unsigned* gc = gcnt + (size_t)b*4096;
  float*    gs = gsum + (size_t)b*4096;
  for (int i=t;i<4096;i+=256){
    if (hc[i]){ atomicAdd(&gc[i], hc[i]); atomicAdd(&gs[i], hs[i]); }
  }
}

__global__ void scanE_kernel(const unsigned* __restrict__ gcnt,
                             const float* __restrict__ gsum,
                             const int* __restrict__ ppos,
                             int* __restrict__ n_pos,
                             double* __restrict__ phard){
  int b = blockIdx.x, t = threadIdx.x;
  __shared__ unsigned sh[256];
  __shared__ int s_sel, s_krem;
  __shared__ double sd[256];
  // fold n_pos reduce: sum this batch's WPB wave partials
  sh[t] = (t < WPB) ? (unsigned)ppos[b*WPB + t] : 0u;
  __syncthreads();
  for (int st=128; st>0; st>>=1){ if (t<st) sh[t]+=sh[t+st]; __syncthreads(); }
  if (t==0) n_pos[b] = (int)sh[0];
  int K = 2*(int)sh[0];
  __syncthreads();
  if (K <= 0){ if (t==0) phard[b] = 0.0; return; }
  const unsigned* gc = gcnt + (size_t)b*4096;
  const float*    gs = gsum + (size_t)b*4096;
  unsigned cnt[16]; float sm[16];
  unsigned ts = 0;
  #pragma unroll
  for (int i=0;i<16;i++){ cnt[i]=gc[t*16+i]; sm[i]=gs[t*16+i]; ts+=cnt[i]; }
  if (t==0){ s_sel = -1; s_krem = 0; }
  sh[t]=ts;
  __syncthreads();
  for (int off=1; off<256; off<<=1){
    unsigned v = (t+off<256)? sh[t+off]:0u;   // read (after barrier)
    __syncthreads();
    sh[t]+=v;                                  // write
    __syncthreads();
  }
  if (K >= Pn){
    double ds=0.0;
    #pragma unroll
    for (int i=0;i<16;i++) ds += (double)sm[i];
    sd[t]=ds; __syncthreads();
    for (int st=128;st>0;st>>=1){ if(t<st) sd[t]+=sd[t+st]; __syncthreads(); }
    if (t==0) phard[b]=sd[0];
    return;
  }
  unsigned incl = sh[t];           // count of keys in bins >= this thread's lowest
  unsigned above = incl - ts;      // count in strictly-higher threads' bins
  if ((int)above < K && K <= (int)incl){
    int acc = (int)above;
    #pragma unroll
    for (int i=15;i>=0;i--){
      acc += (int)cnt[i];
      if (acc >= K){
        s_sel  = t*16 + i;
        s_krem = K - (acc - (int)cnt[i]);
        break;
      }
    }
  }
  __syncthreads();
  int sel = s_sel;
  double ds = 0.0;
  #pragma unroll
  for (int i=0;i<16;i++){ int idx=t*16+i; if (idx > sel) ds += (double)sm[i]; }
  sd[t]=ds; __syncthreads();
  for (int st=128;st>0;st>>=1){ if(t<st) sd[t]+=sd[t+st]; __syncthreads(); }
  if (t==0){
    // tie bin approximated by its midpoint (bounded error, / total_pos in output)
    float vmid = __uint_as_float(((unsigned)sel<<20) | 0x80000u);
    phard[b] = sd[0] + (double)s_krem * (double)vmid;
  }
}

// ---- final combine: sum all partial arrays in doubles ----
__global__ void final_kernel(const int* __restrict__ n_pos,
                             const float* __restrict__ pseg,
                             const float* __restrict__ ploc,
                             const float* __restrict__ pconf,
                             const double* __restrict__ phard,
                             float* __restrict__ out){
  int t = threadIdx.x;
  double seg_s=0.0, loc_s=0.0, conf_s=0.0, hard_s=0.0;
  for (int i=t;i<Bn*WPB;i+=256)   seg_s  += (double)pseg[i];
  for (int i=t;i<Bn*WPB;i+=256)   loc_s  += (double)ploc[i];
  for (int i=t;i<Bn*WPB;i+=256)   conf_s += (double)pconf[i];
  for (int i=t;i<Bn;i+=256)       hard_s += phard[i];
  int tp_s = (t < Bn) ? n_pos[t] : 0;
  __shared__ double sd[256];
  __shared__ int    si_[256];
  si_[t]=tp_s;
  sd[t]=seg_s;  __syncthreads();
  for (int st=128;st>0;st>>=1){ if(t<st){ sd[t]+=sd[t+st]; si_[t]+=si_[t+st]; } __syncthreads(); }
  double seg_t = sd[0]; int tp = si_[0];
  __syncthreads();
  sd[t]=loc_s;  __syncthreads();
  for (int st=128;st>0;st>>=1){ if(t<st) sd[t]+=sd[t+st]; __syncthreads(); }
  double loc_t = sd[0];
  __syncthreads();
  sd[t]=conf_s+hard_s; __syncthreads();
  for (int st=128;st>0;st>>=1){ if(t<st) sd[t]+=sd[t+st]; __syncthreads(); }
  double conf_t = sd[0];
  if (t==0){
    float total = (float)tp;
    float conf_loss = (float)conf_t / total;
    float loc_loss  = (float)loc_t / total;
    float seg_loss  = -(float)seg_t;
    out[0] = conf_loss + loc_loss + seg_loss;
  }
}

extern "C" void kernel_launch(void* const* d_in, const int* in_sizes, int n_in,
                              void* d_out, int out_size, void* d_ws, size_t ws_size,
                              hipStream_t stream) {
  const float* odm_locs   = (const float*)d_in[0];
  const float* odm_scores = (const float*)d_in[1];
  const float* att        = (const float*)d_in[2];
  const float* boxes      = (const float*)d_in[3];
  const int*   labels     = (const int*)d_in[4];
  const float* ign        = (const float*)d_in[5];
  const float* priors     = (const float*)d_in[6];
  float* out = (float*)d_out;

  size_t np = (size_t)Bn * Pn;
  float* ov_prior  = (float*)d_ws;                 // B*P f32
  int*   objinfo   = (int*)(ov_prior + np);        // B*P i32
  float* conf_neg  = (float*)(objinfo + np);       // B*P f32
  unsigned long long* key_obj = (unsigned long long*)(conf_neg + np); // B*O u64
  double* phard    = (double*)(key_obj + (size_t)Bn*On); // Bn f64
  int*    n_pos    = (int*)(phard + Bn);                 // B i32
  float*  pseg     = (float*)(n_pos + Bn);               // B*WPB f32
  float*  ploc     = pseg + (size_t)Bn*WPB;              // B*WPB f32
  float*  pconf    = ploc + (size_t)Bn*WPB;              // B*WPB f32
  int*    ppos     = (int*)(pconf + (size_t)Bn*WPB);     // B*WPB i32

  // radix-select scratch in the ov_prior region (dead after phaseD):
  unsigned* gcnt0 = (unsigned*)ov_prior;
  float*    gsum0 = (float*)(gcnt0 + (size_t)Bn*4096);

  // only key_obj needs zeroing (atomicMax targets); partials fully written
  hipMemsetAsync(key_obj, 0, (size_t)Bn*On*8, stream);

  matchAB_kernel<<<dim3(FBLK, Bn), 256, 0, stream>>>(boxes, ign, priors,
                                                     ov_prior, objinfo, key_obj);
  phaseD_kernel<<<dim3(DBLK, Bn), 256, 0, stream>>>(odm_locs, odm_scores, boxes, labels,
                                                    priors, ov_prior, objinfo, att, key_obj,
                                                    conf_neg, ploc, pconf, ppos, pseg);
  // ov_prior dead from here; reuse as radix scratch (stream-ordered after phaseD)
  hipMemsetAsync(gcnt0, 0, 2*(size_t)Bn*4096*sizeof(unsigned), stream);
  histE_kernel<<<dim3(CHn, Bn), 256, 0, stream>>>(conf_neg, gcnt0, gsum0);
  scanE_kernel<<<Bn, 256, 0, stream>>>(gcnt0, gsum0, ppos, n_pos, phard);
  final_kernel<<<1, 256, 0, stream>>>(n_pos, pseg, ploc, pconf, phard, out);
}

// Round 28
// 157.216 us; speedup vs baseline: 1.0153x; 1.0153x over previous
//
#include <hip/hip_runtime.h>
#include <math.h>

#define Bn 32
#define Pn 42840
#define On 64
#define NIn 8
#define Cn 11
#define ATT_N (32*56*96)
#define THRESHOLD_F 0.4f
#define THETA_F 0.1f
#define CHn 16
#define CHUNK ((Pn + CHn - 1)/CHn)
#define DBLK 42         /* phaseD blocks per batch */
#define WPB  (DBLK*4)   /* phaseD waves per batch = 168 */
#define FP 4            /* priors per thread in matchAB */
#define FBLK ((Pn + 256*FP - 1)/(256*FP))   /* 42 blocks per batch */

// opaque register pin: read-write empty asm -> compiler cannot rematerialize
#define PINF(x) asm volatile("" : "+v"(x))

// ---- fused match: ONE pass over the O x P iou matrix reduces BOTH axes ----
// __launch_bounds__(256,6): <=85 VGPR budget (kernel uses 40 -> no squeeze),
// allows 6 blocks/CU vs (256,4)'s 4. ((256,8) made the allocator clamp to
// 32 VGPR and spill 48MB of scratch -- measured r27.)
__global__ void __launch_bounds__(256, 6)
matchAB_kernel(const float* __restrict__ boxes,
               const float* __restrict__ ign,
               const float* __restrict__ priors,
               float* __restrict__ ov_prior,
               int* __restrict__ objinfo,
               unsigned long long* __restrict__ key_obj){
  __shared__ float4 sbox[On];
  __shared__ float  sar[On];
  __shared__ float4 ibox[NIn];
  __shared__ float  iar[NIn];
  __shared__ unsigned long long skey[On];
  int b = blockIdx.y, t = threadIdx.x;
  if (t < On){
    float4 v = ((const float4*)boxes)[b*On + t];
    sbox[t]=v; sar[t]=(v.z-v.x)*(v.w-v.y);
    skey[t]=0ull;
  } else if (t < On+NIn){
    int o = t - On;
    float4 v = ((const float4*)ign)[b*NIn + o];
    ibox[o]=v; iar[o]=(v.z-v.x)*(v.w-v.y);
  }
  __syncthreads();
  int p0 = (blockIdx.x*256 + t)*FP;
  bool active = (p0 < Pn);          // Pn%4==0 -> all 4 valid when active
  float px1[FP], py1[FP], px2[FP], py2[FP], pab[FP];
  #pragma unroll
  for (int q=0;q<FP;q++){
    float4 pc = active ? ((const float4*)priors)[p0+q]
                       : make_float4(0.f,0.f,0.f,0.f);
    px1[q]=pc.x - pc.z*0.5f; py1[q]=pc.y - pc.w*0.5f;
    px2[q]=pc.x + pc.z*0.5f; py2[q]=pc.y + pc.w*0.5f;
    pab[q]=(px2[q]-px1[q])*(py2[q]-py1[q]);
    PINF(px1[q]); PINF(py1[q]); PINF(px2[q]); PINF(py2[q]); PINF(pab[q]);
  }
  float best[FP]; int bo[FP];
  #pragma unroll
  for (int q=0;q<FP;q++){ best[q]=-1.0f; bo[q]=0; }
  #pragma unroll 1
  for (int o=0;o<On;o++){
    float4 ob = sbox[o];
    float oar = sar[o];
    float cmax=-1.0f; unsigned cp=0u;
    #pragma unroll
    for (int q=0;q<FP;q++){
      float ltx=fmaxf(ob.x,px1[q]), lty=fmaxf(ob.y,py1[q]);
      float rbx=fminf(ob.z,px2[q]), rby=fminf(ob.w,py2[q]);
      float w=fmaxf(rbx-ltx,0.0f), h=fmaxf(rby-lty,0.0f);
      float inter=w*h;
      float uni=(oar+pab[q])-inter;
      float iou = inter * __builtin_amdgcn_rcpf(uni);
      if (iou > best[q]){ best[q]=iou; bo[q]=o; }   // row argmax, first-occurrence
      if (iou > cmax){ cmax=iou; cp=(unsigned)(p0+q); } // col local, smallest p
    }
    // float-only wave max, then lowest-lane-among-ties = smallest p
    float wm = cmax;
    #pragma unroll
    for (int d=32; d>0; d>>=1)
      wm = fmaxf(wm, __shfl_xor(wm, d, 64));
    unsigned long long ball = __ballot(cmax == wm);
    int leader = __ffsll((long long)ball) - 1;
    if (active && (t & 63) == leader){
      unsigned long long key = ((unsigned long long)__float_as_uint(wm)<<32)
                             | (unsigned long long)(0xFFFFFFFFu - cp);
      atomicMax(&skey[o], key);
    }
  }
  // ignored regions: per-prior max only
  float ib[FP];
  #pragma unroll
  for (int q=0;q<FP;q++) ib[q]=-1.0f;
  #pragma unroll
  for (int j=0;j<NIn;j++){
    float4 jb = ibox[j];
    float jar = iar[j];
    #pragma unroll
    for (int q=0;q<FP;q++){
      float ltx=fmaxf(jb.x,px1[q]), lty=fmaxf(jb.y,py1[q]);
      float rbx=fminf(jb.z,px2[q]), rby=fminf(jb.w,py2[q]);
      float w=fmaxf(rbx-ltx,0.0f), h=fmaxf(rby-lty,0.0f);
      float inter=w*h;
      float uni=(jar+pab[q])-inter;
      ib[q] = fmaxf(ib[q], inter * __builtin_amdgcn_rcpf(uni));
    }
  }
  if (active){
    size_t bp0 = (size_t)b*Pn + p0;
    int in_[FP];
    #pragma unroll
    for (int q=0;q<FP;q++)
      in_[q] = bo[q] | ((ib[q] >= THETA_F) ? 256 : 0);
    *(float4*)(ov_prior + bp0) = make_float4(best[0],best[1],best[2],best[3]);
    *(int4*)(objinfo + bp0)    = make_int4(in_[0],in_[1],in_[2],in_[3]);
  }
  __syncthreads();
  if (t < On) atomicMax(&key_obj[(size_t)b*On + t], skey[t]);
}

// ---- phase D: 4 priors/thread + folded seg + fused phaseC winner-list ----
__global__ void __launch_bounds__(256, 4)
phaseD_kernel(const float* __restrict__ odm_locs,
              const float* __restrict__ odm_scores,
              const float* __restrict__ boxes,
              const int* __restrict__ labels,
              const float* __restrict__ priors,
              const float* __restrict__ ov_prior,
              const int* __restrict__ objinfo,
              const float* __restrict__ att,
              const unsigned long long* __restrict__ key_obj,
              float* __restrict__ conf_neg,
              float* __restrict__ ploc,
              float* __restrict__ pconf,
              int* __restrict__ ppos,
              float* __restrict__ pseg){
  int b = blockIdx.y;
  int t = threadIdx.x;
  // winner list for this block's prior range [pbase, pbase+1024)
  __shared__ int wl_p[On];
  __shared__ int wl_rank[On];
  __shared__ int wl_n;
  int pbase = blockIdx.x*1024;
  if (t == 0) wl_n = 0;
  __syncthreads();
  if (t < On){                          // first wave only
    unsigned long long k = key_obj[(size_t)b*On + t];
    bool valid = (unsigned)(k>>32) > 0u;
    unsigned long long ball = __ballot(valid);
    int rank = (int)__popcll(ball & ((1ull<<t) - 1ull));  // cumsum(valid)-1
    if (valid){
      int p = (int)(0xFFFFFFFFu - (unsigned)(k & 0xFFFFFFFFu));
      if (p >= pbase && p < pbase + 1024){
        int idx = atomicAdd(&wl_n, 1);
        wl_p[idx] = p; wl_rank[idx] = rank;
      }
    }
  }
  // folded seg: phaseD has 1344*256 = 344064 threads >= ATT_N = 172032
  int gid = (b*DBLK + blockIdx.x)*256 + t;
  float segv = 0.0f;
  if (gid < ATT_N) segv = fmaxf(log1pf(-att[gid]), -100.0f);
  __syncthreads();
  int nwl = wl_n;
  int p0 = pbase + t*4;
  float locv = 0.0f, confpv = 0.0f; int posv = 0;
  if (p0 < Pn){                           // Pn%4==0 -> all 4 priors valid
    size_t bp0 = (size_t)b*Pn + p0;
    float4 sc4[11];
    const float4* src = (const float4*)(odm_scores + bp0*Cn);  // 16B-aligned
    #pragma unroll
    for (int i=0;i<11;i++) sc4[i] = src[i];
    int4   info4 = *(const int4*)(objinfo + bp0);
    float4 ovp4  = *(const float4*)(ov_prior + bp0);
    const float* sc = (const float*)sc4;   // constant indices only (post-unroll)
    float cn[4];
    #pragma unroll
    for (int j=0;j<4;j++){
      int info = (&info4.x)[j];
      int obj = info & 0xFF;
      bool ignored = (info & 256) != 0;
      float ov = (&ovp4.x)[j];
      // winner override: obj -> rank (max over duplicates == last-write-wins), ov -> 1.0
      int ovr = -1;
      for (int i=0;i<nwl;i++)
        if (wl_p[i] == p0+j) ovr = max(ovr, wl_rank[i]);
      if (ovr >= 0){ obj = ovr; ov = 1.0f; }
      int label = labels[b*On + obj];
      if (ov < THRESHOLD_F) label = 0;
      bool pos = label > 0;
      float m = sc[j*Cn];
      #pragma unroll
      for (int c=1;c<Cn;c++) m = fmaxf(m, sc[j*Cn+c]);
      float se = 0.0f, slab = 0.0f;
      #pragma unroll
      for (int c=0;c<Cn;c++){
        float v = sc[j*Cn+c];
        se += expf(v-m);
        if (c == label) slab = v;          // c is compile-time -> cndmask chain
      }
      float conf = logf(se) - (slab-m);
      cn[j] = (pos || ignored) ? 0.0f : conf;
      if (pos){
        posv += 1; confpv += conf;
        size_t bp = bp0 + j;
        float4 pc = ((const float4*)priors)[p0+j];
        float4 g  = ((const float4*)odm_locs)[bp];
        float cx = g.x*pc.z/10.0f + pc.x;
        float cy = g.y*pc.w/10.0f + pc.y;
        float w  = expf(g.z/5.0f)*pc.z;
        float h  = expf(g.w/5.0f)*pc.w;
        float dx1 = cx - w/2.0f, dy1 = cy - h/2.0f;
        float dx2 = cx + w/2.0f, dy2 = cy + h/2.0f;
        const float* gt = boxes + ((size_t)b*On + obj)*4;
        float gx1=gt[0], gy1=gt[1], gx2=gt[2], gy2=gt[3];
        float ltx=fmaxf(dx1,gx1), lty=fmaxf(dy1,gy1);
        float rbx=fminf(dx2,gx2), rby=fminf(dy2,gy2);
        float iw=fmaxf(rbx-ltx,0.0f), ih=fmaxf(rby-lty,0.0f);
        float inter=iw*ih;
        float ap=(dx2-dx1)*(dy2-dy1);
        float ag=(gx2-gx1)*(gy2-gy1);
        float iou = inter/((ap+ag)-inter);
        float cpx=(dx1+dx2)/2.0f, cpy=(dy1+dy2)/2.0f;
        float cgx=(gx1+gx2)/2.0f, cgy=(gy1+gy2)/2.0f;
        float ddx=cpx-cgx, ddy=cpy-cgy;
        float inter_diag = ddx*ddx + ddy*ddy;
        float cltx=fminf(dx1,gx1), clty=fminf(dy1,gy1);
        float crbx=fmaxf(dx2,gx2), crby=fmaxf(dy2,gy2);
        float odx=crbx-cltx, ody=crby-clty;
        float outer_diag = odx*odx + ody*ody;
        float diou = fminf(fmaxf(iou - inter_diag/outer_diag, -1.0f), 1.0f);
        locv += 1.0f - diou;
      }
    }
    *(float4*)(conf_neg + bp0) = make_float4(cn[0],cn[1],cn[2],cn[3]);
  }
  // per-wave butterfly reduction, lane 0 writes a unique slot -> zero contention
  #pragma unroll
  for (int d=32; d>0; d>>=1){
    locv   += __shfl_xor(locv,   d, 64);
    confpv += __shfl_xor(confpv, d, 64);
    posv   += __shfl_xor(posv,   d, 64);
    segv   += __shfl_xor(segv,   d, 64);
  }
  if ((t & 63) == 0){
    int widx = b*WPB + (blockIdx.x<<2) + (t>>6);
    ploc[widx]  = locv;
    pconf[widx] = confpv;
    ppos[widx]  = posv;
    pseg[widx]  = segv;
  }
}

// ---- phase E: SINGLE-round 12-bit radix select with per-bin (count,sum) ----
__global__ void histE_kernel(const float* __restrict__ conf_neg,
                             unsigned* __restrict__ gcnt,
                             float* __restrict__ gsum){
  int b = blockIdx.y, c = blockIdx.x, t = threadIdx.x;
  __shared__ unsigned hc[4096];
  __shared__ float    hs[4096];
  for (int i=t;i<4096;i+=256){ hc[i]=0u; hs[i]=0.0f; }
  __syncthreads();
  const float* cn = conf_neg + (size_t)b*Pn;
  int p0 = c*CHUNK, p1 = min(Pn, p0+CHUNK);
  for (int p=p0+t; p<p1; p+=256){
    float v = cn[p];
    unsigned d = __float_as_uint(v)>>20;   // v >= 0 -> uint order == float order
    atomicAdd(&hc[d],1u); atomicAdd(&hs[d],v);
  }
  __syncthreads();
  unsigned* gc = gcnt + (size_t)b*4096;
  float*    gs = gsum + (size_t)b*4096;
  for (int i=t;i<4096;i+=256){
    if (hc[i]){ atomicAdd(&gc[i], hc[i]); atomicAdd(&gs[i], hs[i]); }
  }
}

__global__ void scanE_kernel(const unsigned* __restrict__ gcnt,
                             const float* __restrict__ gsum,
                             const int* __restrict__ ppos,
                             int* __restrict__ n_pos,
                             double* __restrict__ phard){
  int b = blockIdx.x, t = threadIdx.x;
  __shared__ unsigned sh[256];
  __shared__ int s_sel, s_krem;
  __shared__ double sd[256];
  // fold n_pos reduce: sum this batch's WPB wave partials
  sh[t] = (t < WPB) ? (unsigned)ppos[b*WPB + t] : 0u;
  __syncthreads();
  for (int st=128; st>0; st>>=1){ if (t<st) sh[t]+=sh[t+st]; __syncthreads(); }
  if (t==0) n_pos[b] = (int)sh[0];
  int K = 2*(int)sh[0];
  __syncthreads();
  if (K <= 0){ if (t==0) phard[b] = 0.0; return; }
  const unsigned* gc = gcnt + (size_t)b*4096;
  const float*    gs = gsum + (size_t)b*4096;
  unsigned cnt[16]; float sm[16];
  unsigned ts = 0;
  #pragma unroll
  for (int i=0;i<16;i++){ cnt[i]=gc[t*16+i]; sm[i]=gs[t*16+i]; ts+=cnt[i]; }
  if (t==0){ s_sel = -1; s_krem = 0; }
  sh[t]=ts;
  __syncthreads();
  for (int off=1; off<256; off<<=1){
    unsigned v = (t+off<256)? sh[t+off]:0u;   // read (after barrier)
    __syncthreads();
    sh[t]+=v;                                  // write
    __syncthreads();
  }
  if (K >= Pn){
    double ds=0.0;
    #pragma unroll
    for (int i=0;i<16;i++) ds += (double)sm[i];
    sd[t]=ds; __syncthreads();
    for (int st=128;st>0;st>>=1){ if(t<st) sd[t]+=sd[t+st]; __syncthreads(); }
    if (t==0) phard[b]=sd[0];
    return;
  }
  unsigned incl = sh[t];           // count of keys in bins >= this thread's lowest
  unsigned above = incl - ts;      // count in strictly-higher threads' bins
  if ((int)above < K && K <= (int)incl){
    int acc = (int)above;
    #pragma unroll
    for (int i=15;i>=0;i--){
      acc += (int)cnt[i];
      if (acc >= K){
        s_sel  = t*16 + i;
        s_krem = K - (acc - (int)cnt[i]);
        break;
      }
    }
  }
  __syncthreads();
  int sel = s_sel;
  double ds = 0.0;
  #pragma unroll
  for (int i=0;i<16;i++){ int idx=t*16+i; if (idx > sel) ds += (double)sm[i]; }
  sd[t]=ds; __syncthreads();
  for (int st=128;st>0;st>>=1){ if(t<st) sd[t]+=sd[t+st]; __syncthreads(); }
  if (t==0){
    // tie bin approximated by its midpoint (bounded error, / total_pos in output)
    float vmid = __uint_as_float(((unsigned)sel<<20) | 0x80000u);
    phard[b] = sd[0] + (double)s_krem * (double)vmid;
  }
}

// ---- final combine: sum all partial arrays in doubles ----
__global__ void final_kernel(const int* __restrict__ n_pos,
                             const float* __restrict__ pseg,
                             const float* __restrict__ ploc,
                             const float* __restrict__ pconf,
                             const double* __restrict__ phard,
                             float* __restrict__ out){
  int t = threadIdx.x;
  double seg_s=0.0, loc_s=0.0, conf_s=0.0, hard_s=0.0;
  for (int i=t;i<Bn*WPB;i+=256)   seg_s  += (double)pseg[i];
  for (int i=t;i<Bn*WPB;i+=256)   loc_s  += (double)ploc[i];
  for (int i=t;i<Bn*WPB;i+=256)   conf_s += (double)pconf[i];
  for (int i=t;i<Bn;i+=256)       hard_s += phard[i];
  int tp_s = (t < Bn) ? n_pos[t] : 0;
  __shared__ double sd[256];
  __shared__ int    si_[256];
  si_[t]=tp_s;
  sd[t]=seg_s;  __syncthreads();
  for (int st=128;st>0;st>>=1){ if(t<st){ sd[t]+=sd[t+st]; si_[t]+=si_[t+st]; } __syncthreads(); }
  double seg_t = sd[0]; int tp = si_[0];
  __syncthreads();
  sd[t]=loc_s;  __syncthreads();
  for (int st=128;st>0;st>>=1){ if(t<st) sd[t]+=sd[t+st]; __syncthreads(); }
  double loc_t = sd[0];
  __syncthreads();
  sd[t]=conf_s+hard_s; __syncthreads();
  for (int st=128;st>0;st>>=1){ if(t<st) sd[t]+=sd[t+st]; __syncthreads(); }
  double conf_t = sd[0];
  if (t==0){
    float total = (float)tp;
    float conf_loss = (float)conf_t / total;
    float loc_loss  = (float)loc_t / total;
    float seg_loss  = -(float)seg_t;
    out[0] = conf_loss + loc_loss + seg_loss;
  }
}

extern "C" void kernel_launch(void* const* d_in, const int* in_sizes, int n_in,
                              void* d_out, int out_size, void* d_ws, size_t ws_size,
                              hipStream_t stream) {
  const float* odm_locs   = (const float*)d_in[0];
  const float* odm_scores = (const float*)d_in[1];
  const float* att        = (const float*)d_in[2];
  const float* boxes      = (const float*)d_in[3];
  const int*   labels     = (const int*)d_in[4];
  const float* ign        = (const float*)d_in[5];
  const float* priors     = (const float*)d_in[6];
  float* out = (float*)d_out;

  size_t np = (size_t)Bn * Pn;
  float* ov_prior  = (float*)d_ws;                 // B*P f32
  int*   objinfo   = (int*)(ov_prior + np);        // B*P i32
  float* conf_neg  = (float*)(objinfo + np);       // B*P f32
  unsigned long long* key_obj = (unsigned long long*)(conf_neg + np); // B*O u64
  double* phard    = (double*)(key_obj + (size_t)Bn*On); // Bn f64
  int*    n_pos    = (int*)(phard + Bn);                 // B i32
  float*  pseg     = (float*)(n_pos + Bn);               // B*WPB f32
  float*  ploc     = pseg + (size_t)Bn*WPB;              // B*WPB f32
  float*  pconf    = ploc + (size_t)Bn*WPB;              // B*WPB f32
  int*    ppos     = (int*)(pconf + (size_t)Bn*WPB);     // B*WPB i32

  // radix-select scratch in the ov_prior region (dead after phaseD):
  unsigned* gcnt0 = (unsigned*)ov_prior;
  float*    gsum0 = (float*)(gcnt0 + (size_t)Bn*4096);

  // only key_obj needs zeroing (atomicMax targets); partials fully written
  hipMemsetAsync(key_obj, 0, (size_t)Bn*On*8, stream);

  matchAB_kernel<<<dim3(FBLK, Bn), 256, 0, stream>>>(boxes, ign, priors,
                                                     ov_prior, objinfo, key_obj);
  phaseD_kernel<<<dim3(DBLK, Bn), 256, 0, stream>>>(odm_locs, odm_scores, boxes, labels,
                                                    priors, ov_prior, objinfo, att, key_obj,
                                                    conf_neg, ploc, pconf, ppos, pseg);
  // ov_prior dead from here; reuse as radix scratch (stream-ordered after phaseD)
  hipMemsetAsync(gcnt0, 0, 2*(size_t)Bn*4096*sizeof(unsigned), stream);
  histE_kernel<<<dim3(CHn, Bn), 256, 0, stream>>>(conf_neg, gcnt0, gsum0);
  scanE_kernel<<<Bn, 256, 0, stream>>>(gcnt0, gsum0, ppos, n_pos, phard);
  final_kernel<<<1, 256, 0, stream>>>(n_pos, pseg, ploc, pconf, phard, out);
}

// Round 29
// 155.927 us; speedup vs baseline: 1.0237x; 1.0083x over previous
//
#include <hip/hip_runtime.h>
#include <math.h>

#define Bn 32
#define Pn 42840
#define On 64
#define NIn 8
#define Cn 11
#define ATT_N (32*56*96)
#define THRESHOLD_F 0.4f
#define THETA_F 0.1f
#define CHn 16
#define CHUNK ((Pn + CHn - 1)/CHn)
#define DBLK 42         /* phaseD blocks per batch */
#define WPB  (DBLK*4)   /* phaseD waves per batch = 168 */
#define FP 4            /* priors per thread in matchAB */
#define FBLK ((Pn + 256*FP - 1)/(256*FP))   /* 42 blocks per batch */

// opaque register pin: read-write empty asm -> compiler cannot rematerialize
#define PINF(x) asm volatile("" : "+v"(x))

// ---- fused match: ONE pass over the O x P iou matrix reduces BOTH axes ----
__global__ void __launch_bounds__(256, 4)
matchAB_kernel(const float* __restrict__ boxes,
               const float* __restrict__ ign,
               const float* __restrict__ priors,
               float* __restrict__ ov_prior,
               int* __restrict__ objinfo,
               unsigned long long* __restrict__ key_obj){
  __shared__ float4 sbox[On];
  __shared__ float  sar[On];
  __shared__ float4 ibox[NIn];
  __shared__ float  iar[NIn];
  __shared__ unsigned long long skey[On];
  int b = blockIdx.y, t = threadIdx.x;
  if (t < On){
    float4 v = ((const float4*)boxes)[b*On + t];
    sbox[t]=v; sar[t]=(v.z-v.x)*(v.w-v.y);
    skey[t]=0ull;
  } else if (t < On+NIn){
    int o = t - On;
    float4 v = ((const float4*)ign)[b*NIn + o];
    ibox[o]=v; iar[o]=(v.z-v.x)*(v.w-v.y);
  }
  __syncthreads();
  int p0 = (blockIdx.x*256 + t)*FP;
  bool active = (p0 < Pn);          // Pn%4==0 -> all 4 valid when active
  float px1[FP], py1[FP], px2[FP], py2[FP], pab[FP];
  #pragma unroll
  for (int q=0;q<FP;q++){
    float4 pc = active ? ((const float4*)priors)[p0+q]
                       : make_float4(0.f,0.f,0.f,0.f);
    px1[q]=pc.x - pc.z*0.5f; py1[q]=pc.y - pc.w*0.5f;
    px2[q]=pc.x + pc.z*0.5f; py2[q]=pc.y + pc.w*0.5f;
    pab[q]=(px2[q]-px1[q])*(py2[q]-py1[q]);
    PINF(px1[q]); PINF(py1[q]); PINF(px2[q]); PINF(py2[q]); PINF(pab[q]);
  }
  float best[FP]; int bo[FP];
  #pragma unroll
  for (int q=0;q<FP;q++){ best[q]=-1.0f; bo[q]=0; }
  #pragma unroll 1
  for (int o=0;o<On;o++){
    float4 ob = sbox[o];
    float oar = sar[o];
    float cmax=-1.0f; unsigned cp=0u;
    #pragma unroll
    for (int q=0;q<FP;q++){
      float ltx=fmaxf(ob.x,px1[q]), lty=fmaxf(ob.y,py1[q]);
      float rbx=fminf(ob.z,px2[q]), rby=fminf(ob.w,py2[q]);
      float w=fmaxf(rbx-ltx,0.0f), h=fmaxf(rby-lty,0.0f);
      float inter=w*h;
      float uni=(oar+pab[q])-inter;
      float iou = inter * __builtin_amdgcn_rcpf(uni);
      if (iou > best[q]){ best[q]=iou; bo[q]=o; }   // row argmax, first-occurrence
      if (iou > cmax){ cmax=iou; cp=(unsigned)(p0+q); } // col local, smallest p
    }
    // float-only wave max, then lowest-lane-among-ties = smallest p
    float wm = cmax;
    #pragma unroll
    for (int d=32; d>0; d>>=1)
      wm = fmaxf(wm, __shfl_xor(wm, d, 64));
    unsigned long long ball = __ballot(cmax == wm);
    int leader = __ffsll((long long)ball) - 1;
    if (active && (t & 63) == leader){
      unsigned long long key = ((unsigned long long)__float_as_uint(wm)<<32)
                             | (unsigned long long)(0xFFFFFFFFu - cp);
      atomicMax(&skey[o], key);
    }
  }
  // ignored regions: per-prior max only
  float ib[FP];
  #pragma unroll
  for (int q=0;q<FP;q++) ib[q]=-1.0f;
  #pragma unroll
  for (int j=0;j<NIn;j++){
    float4 jb = ibox[j];
    float jar = iar[j];
    #pragma unroll
    for (int q=0;q<FP;q++){
      float ltx=fmaxf(jb.x,px1[q]), lty=fmaxf(jb.y,py1[q]);
      float rbx=fminf(jb.z,px2[q]), rby=fminf(jb.w,py2[q]);
      float w=fmaxf(rbx-ltx,0.0f), h=fmaxf(rby-lty,0.0f);
      float inter=w*h;
      float uni=(jar+pab[q])-inter;
      ib[q] = fmaxf(ib[q], inter * __builtin_amdgcn_rcpf(uni));
    }
  }
  if (active){
    size_t bp0 = (size_t)b*Pn + p0;
    int in_[FP];
    #pragma unroll
    for (int q=0;q<FP;q++)
      in_[q] = bo[q] | ((ib[q] >= THETA_F) ? 256 : 0);
    *(float4*)(ov_prior + bp0) = make_float4(best[0],best[1],best[2],best[3]);
    *(int4*)(objinfo + bp0)    = make_int4(in_[0],in_[1],in_[2],in_[3]);
  }
  __syncthreads();
  if (t < On) atomicMax(&key_obj[(size_t)b*On + t], skey[t]);
}

// ---- phase D: 4 priors/thread + folded seg + fused phaseC winner-list ----
__global__ void __launch_bounds__(256, 4)
phaseD_kernel(const float* __restrict__ odm_locs,
              const float* __restrict__ odm_scores,
              const float* __restrict__ boxes,
              const int* __restrict__ labels,
              const float* __restrict__ priors,
              const float* __restrict__ ov_prior,
              const int* __restrict__ objinfo,
              const float* __restrict__ att,
              const unsigned long long* __restrict__ key_obj,
              float* __restrict__ conf_neg,
              float* __restrict__ ploc,
              float* __restrict__ pconf,
              int* __restrict__ ppos,
              float* __restrict__ pseg){
  int b = blockIdx.y;
  int t = threadIdx.x;
  // winner list for this block's prior range [pbase, pbase+1024)
  __shared__ int wl_p[On];
  __shared__ int wl_rank[On];
  __shared__ int wl_n;
  int pbase = blockIdx.x*1024;
  if (t == 0) wl_n = 0;
  __syncthreads();
  if (t < On){                          // first wave only
    unsigned long long k = key_obj[(size_t)b*On + t];
    bool valid = (unsigned)(k>>32) > 0u;
    unsigned long long ball = __ballot(valid);
    int rank = (int)__popcll(ball & ((1ull<<t) - 1ull));  // cumsum(valid)-1
    if (valid){
      int p = (int)(0xFFFFFFFFu - (unsigned)(k & 0xFFFFFFFFu));
      if (p >= pbase && p < pbase + 1024){
        int idx = atomicAdd(&wl_n, 1);
        wl_p[idx] = p; wl_rank[idx] = rank;
      }
    }
  }
  // folded seg: phaseD has 1344*256 = 344064 threads >= ATT_N = 172032
  int gid = (b*DBLK + blockIdx.x)*256 + t;
  float segv = 0.0f;
  if (gid < ATT_N) segv = fmaxf(log1pf(-att[gid]), -100.0f);
  __syncthreads();
  int nwl = wl_n;
  int p0 = pbase + t*4;
  float locv = 0.0f, confpv = 0.0f; int posv = 0;
  if (p0 < Pn){                           // Pn%4==0 -> all 4 priors valid
    size_t bp0 = (size_t)b*Pn + p0;
    float4 sc4[11];
    const float4* src = (const float4*)(odm_scores + bp0*Cn);  // 16B-aligned
    #pragma unroll
    for (int i=0;i<11;i++) sc4[i] = src[i];
    int4   info4 = *(const int4*)(objinfo + bp0);
    float4 ovp4  = *(const float4*)(ov_prior + bp0);
    const float* sc = (const float*)sc4;   // constant indices only (post-unroll)
    float cn[4];
    #pragma unroll
    for (int j=0;j<4;j++){
      int info = (&info4.x)[j];
      int obj = info & 0xFF;
      bool ignored = (info & 256) != 0;
      float ov = (&ovp4.x)[j];
      // winner override: obj -> rank (max over duplicates == last-write-wins), ov -> 1.0
      int ovr = -1;
      for (int i=0;i<nwl;i++)
        if (wl_p[i] == p0+j) ovr = max(ovr, wl_rank[i]);
      if (ovr >= 0){ obj = ovr; ov = 1.0f; }
      int label = labels[b*On + obj];
      if (ov < THRESHOLD_F) label = 0;
      bool pos = label > 0;
      float m = sc[j*Cn];
      #pragma unroll
      for (int c=1;c<Cn;c++) m = fmaxf(m, sc[j*Cn+c]);
      float se = 0.0f, slab = 0.0f;
      #pragma unroll
      for (int c=0;c<Cn;c++){
        float v = sc[j*Cn+c];
        se += expf(v-m);
        if (c == label) slab = v;          // c is compile-time -> cndmask chain
      }
      float conf = logf(se) - (slab-m);
      cn[j] = (pos || ignored) ? 0.0f : conf;
      if (pos){
        posv += 1; confpv += conf;
        size_t bp = bp0 + j;
        float4 pc = ((const float4*)priors)[p0+j];
        float4 g  = ((const float4*)odm_locs)[bp];
        float cx = g.x*pc.z/10.0f + pc.x;
        float cy = g.y*pc.w/10.0f + pc.y;
        float w  = expf(g.z/5.0f)*pc.z;
        float h  = expf(g.w/5.0f)*pc.w;
        float dx1 = cx - w/2.0f, dy1 = cy - h/2.0f;
        float dx2 = cx + w/2.0f, dy2 = cy + h/2.0f;
        const float* gt = boxes + ((size_t)b*On + obj)*4;
        float gx1=gt[0], gy1=gt[1], gx2=gt[2], gy2=gt[3];
        float ltx=fmaxf(dx1,gx1), lty=fmaxf(dy1,gy1);
        float rbx=fminf(dx2,gx2), rby=fminf(dy2,gy2);
        float iw=fmaxf(rbx-ltx,0.0f), ih=fmaxf(rby-lty,0.0f);
        float inter=iw*ih;
        float ap=(dx2-dx1)*(dy2-dy1);
        float ag=(gx2-gx1)*(gy2-gy1);
        float iou = inter/((ap+ag)-inter);
        float cpx=(dx1+dx2)/2.0f, cpy=(dy1+dy2)/2.0f;
        float cgx=(gx1+gx2)/2.0f, cgy=(gy1+gy2)/2.0f;
        float ddx=cpx-cgx, ddy=cpy-cgy;
        float inter_diag = ddx*ddx + ddy*ddy;
        float cltx=fminf(dx1,gx1), clty=fminf(dy1,gy1);
        float crbx=fmaxf(dx2,gx2), crby=fmaxf(dy2,gy2);
        float odx=crbx-cltx, ody=crby-clty;
        float outer_diag = odx*odx + ody*ody;
        float diou = fminf(fmaxf(iou - inter_diag/outer_diag, -1.0f), 1.0f);
        locv += 1.0f - diou;
      }
    }
    *(float4*)(conf_neg + bp0) = make_float4(cn[0],cn[1],cn[2],cn[3]);
  }
  // per-wave butterfly reduction, lane 0 writes a unique slot -> zero contention
  #pragma unroll
  for (int d=32; d>0; d>>=1){
    locv   += __shfl_xor(locv,   d, 64);
    confpv += __shfl_xor(confpv, d, 64);
    posv   += __shfl_xor(posv,   d, 64);
    segv   += __shfl_xor(segv,   d, 64);
  }
  if ((t & 63) == 0){
    int widx = b*WPB + (blockIdx.x<<2) + (t>>6);
    ploc[widx]  = locv;
    pconf[widx] = confpv;
    ppos[widx]  = posv;
    pseg[widx]  = segv;
  }
}

// ---- phase E: SINGLE-round 12-bit radix select with per-bin (count,sum) ----
__global__ void histE_kernel(const float* __restrict__ conf_neg,
                             unsigned* __restrict__ gcnt,
                             float* __restrict__ gsum){
  int b = blockIdx.y, c = blockIdx.x, t = threadIdx.x;
  __shared__ unsigned hc[4096];
  __shared__ float    hs[4096];
  for (int i=t;i<4096;i+=256){ hc[i]=0u; hs[i]=0.0f; }
  __syncthreads();
  const float* cn = conf_neg + (size_t)b*Pn;
  int p0 = c*CHUNK, p1 = min(Pn, p0+CHUNK);
  for (int p=p0+t; p<p1; p+=256){
    float v = cn[p];
    unsigned d = __float_as_uint(v)>>20;   // v >= 0 -> uint order == float order
    atomicAdd(&hc[d],1u); atomicAdd(&hs[d],v);
  }
  __syncthreads();
  unsigned* gc = gcnt + (size_t)b*4096;
  float*    gs = gsum + (size_t)b*4096;
  for (int i=t;i<4096;i+=256){
    if (hc[i]){ atomicAdd(&gc[i], hc[i]); atomicAdd(&gs[i], hs[i]); }
  }
}

__global__ void scanE_kernel(const unsigned* __restrict__ gcnt,
                             const float* __restrict__ gsum,
                             const int* __restrict__ ppos,
                             int* __restrict__ n_pos,
                             double* __restrict__ phard){
  int b = blockIdx.x, t = threadIdx.x;
  __shared__ unsigned sh[256];
  __shared__ int s_sel, s_krem;
  __shared__ double sd[256];
  // fold n_pos reduce: sum this batch's WPB wave partials
  sh[t] = (t < WPB) ? (unsigned)ppos[b*WPB + t] : 0u;
  __syncthreads();
  for (int st=128; st>0; st>>=1){ if (t<st) sh[t]+=sh[t+st]; __syncthreads(); }
  if (t==0) n_pos[b] = (int)sh[0];
  int K = 2*(int)sh[0];
  __syncthreads();
  if (K <= 0){ if (t==0) phard[b] = 0.0; return; }
  const unsigned* gc = gcnt + (size_t)b*4096;
  const float*    gs = gsum + (size_t)b*4096;
  unsigned cnt[16]; float sm[16];
  unsigned ts = 0;
  #pragma unroll
  for (int i=0;i<16;i++){ cnt[i]=gc[t*16+i]; sm[i]=gs[t*16+i]; ts+=cnt[i]; }
  if (t==0){ s_sel = -1; s_krem = 0; }
  sh[t]=ts;
  __syncthreads();
  for (int off=1; off<256; off<<=1){
    unsigned v = (t+off<256)? sh[t+off]:0u;   // read (after barrier)
    __syncthreads();
    sh[t]+=v;                                  // write
    __syncthreads();
  }
  if (K >= Pn){
    double ds=0.0;
    #pragma unroll
    for (int i=0;i<16;i++) ds += (double)sm[i];
    sd[t]=ds; __syncthreads();
    for (int st=128;st>0;st>>=1){ if(t<st) sd[t]+=sd[t+st]; __syncthreads(); }
    if (t==0) phard[b]=sd[0];
    return;
  }
  unsigned incl = sh[t];           // count of keys in bins >= this thread's lowest
  unsigned above = incl - ts;      // count in strictly-higher threads' bins
  if ((int)above < K && K <= (int)incl){
    int acc = (int)above;
    #pragma unroll
    for (int i=15;i>=0;i--){
      acc += (int)cnt[i];
      if (acc >= K){
        s_sel  = t*16 + i;
        s_krem = K - (acc - (int)cnt[i]);
        break;
      }
    }
  }
  __syncthreads();
  int sel = s_sel;
  double ds = 0.0;
  #pragma unroll
  for (int i=0;i<16;i++){ int idx=t*16+i; if (idx > sel) ds += (double)sm[i]; }
  sd[t]=ds; __syncthreads();
  for (int st=128;st>0;st>>=1){ if(t<st) sd[t]+=sd[t+st]; __syncthreads(); }
  if (t==0){
    // tie bin approximated by its midpoint (bounded error, / total_pos in output)
    float vmid = __uint_as_float(((unsigned)sel<<20) | 0x80000u);
    phard[b] = sd[0] + (double)s_krem * (double)vmid;
  }
}

// ---- final combine: sum all partial arrays in doubles ----
__global__ void final_kernel(const int* __restrict__ n_pos,
                             const float* __restrict__ pseg,
                             const float* __restrict__ ploc,
                             const float* __restrict__ pconf,
                             const double* __restrict__ phard,
                             float* __restrict__ out){
  int t = threadIdx.x;
  double seg_s=0.0, loc_s=0.0, conf_s=0.0, hard_s=0.0;
  for (int i=t;i<Bn*WPB;i+=256)   seg_s  += (double)pseg[i];
  for (int i=t;i<Bn*WPB;i+=256)   loc_s  += (double)ploc[i];
  for (int i=t;i<Bn*WPB;i+=256)   conf_s += (double)pconf[i];
  for (int i=t;i<Bn;i+=256)       hard_s += phard[i];
  int tp_s = (t < Bn) ? n_pos[t] : 0;
  __shared__ double sd[256];
  __shared__ int    si_[256];
  si_[t]=tp_s;
  sd[t]=seg_s;  __syncthreads();
  for (int st=128;st>0;st>>=1){ if(t<st){ sd[t]+=sd[t+st]; si_[t]+=si_[t+st]; } __syncthreads(); }
  double seg_t = sd[0]; int tp = si_[0];
  __syncthreads();
  sd[t]=loc_s;  __syncthreads();
  for (int st=128;st>0;st>>=1){ if(t<st) sd[t]+=sd[t+st]; __syncthreads(); }
  double loc_t = sd[0];
  __syncthreads();
  sd[t]=conf_s+hard_s; __syncthreads();
  for (int st=128;st>0;st>>=1){ if(t<st) sd[t]+=sd[t+st]; __syncthreads(); }
  double conf_t = sd[0];
  if (t==0){
    float total = (float)tp;
    float conf_loss = (float)conf_t / total;
    float loc_loss  = (float)loc_t / total;
    float seg_loss  = -(float)seg_t;
    out[0] = conf_loss + loc_loss + seg_loss;
  }
}

extern "C" void kernel_launch(void* const* d_in, const int* in_sizes, int n_in,
                              void* d_out, int out_size, void* d_ws, size_t ws_size,
                              hipStream_t stream) {
  const float* odm_locs   = (const float*)d_in[0];
  const float* odm_scores = (const float*)d_in[1];
  const float* att        = (const float*)d_in[2];
  const float* boxes      = (const float*)d_in[3];
  const int*   labels     = (const int*)d_in[4];
  const float* ign        = (const float*)d_in[5];
  const float* priors     = (const float*)d_in[6];
  float* out = (float*)d_out;

  size_t np = (size_t)Bn * Pn;
  float* ov_prior  = (float*)d_ws;                 // B*P f32
  int*   objinfo   = (int*)(ov_prior + np);        // B*P i32
  float* conf_neg  = (float*)(objinfo + np);       // B*P f32
  unsigned long long* key_obj = (unsigned long long*)(conf_neg + np); // B*O u64
  double* phard    = (double*)(key_obj + (size_t)Bn*On); // Bn f64
  int*    n_pos    = (int*)(phard + Bn);                 // B i32
  float*  pseg     = (float*)(n_pos + Bn);               // B*WPB f32
  float*  ploc     = pseg + (size_t)Bn*WPB;              // B*WPB f32
  float*  pconf    = ploc + (size_t)Bn*WPB;              // B*WPB f32
  int*    ppos     = (int*)(pconf + (size_t)Bn*WPB);     // B*WPB i32

  // radix-select scratch in the ov_prior region (dead after phaseD):
  unsigned* gcnt0 = (unsigned*)ov_prior;
  float*    gsum0 = (float*)(gcnt0 + (size_t)Bn*4096);

  // only key_obj needs zeroing (atomicMax targets); partials fully written
  hipMemsetAsync(key_obj, 0, (size_t)Bn*On*8, stream);

  matchAB_kernel<<<dim3(FBLK, Bn), 256, 0, stream>>>(boxes, ign, priors,
                                                     ov_prior, objinfo, key_obj);
  phaseD_kernel<<<dim3(DBLK, Bn), 256, 0, stream>>>(odm_locs, odm_scores, boxes, labels,
                                                    priors, ov_prior, objinfo, att, key_obj,
                                                    conf_neg, ploc, pconf, ppos, pseg);
  // ov_prior dead from here; reuse as radix scratch (stream-ordered after phaseD)
  hipMemsetAsync(gcnt0, 0, 2*(size_t)Bn*4096*sizeof(unsigned), stream);
  histE_kernel<<<dim3(CHn, Bn), 256, 0, stream>>>(conf_neg, gcnt0, gsum0);
  scanE_kernel<<<Bn, 256, 0, stream>>>(gcnt0, gsum0, ppos, n_pos, phard);
  final_kernel<<<1, 256, 0, stream>>>(n_pos, pseg, ploc, pconf, phard, out);
}